// Round 4
// baseline (500.115 us; speedup 1.0000x reference)
//
#include <hip/hip_runtime.h>

typedef unsigned short u16;
typedef __bf16 bf16x8 __attribute__((ext_vector_type(8)));
typedef float f32x4 __attribute__((ext_vector_type(4)));

__device__ __forceinline__ u16 f2bf(float f) {
  union { float f; unsigned u; } v; v.f = f;
  unsigned r = v.u + 0x7fffu + ((v.u >> 16) & 1u);
  return (u16)(r >> 16);
}

__device__ __forceinline__ void gload_lds16(const void* g, void* l) {
  using gvp = const __attribute__((address_space(1))) void*;
  using lvp = __attribute__((address_space(3))) void*;
  __builtin_amdgcn_global_load_lds((gvp)g, (lvp)l, 16, 0, 0);
}

// ---------------- fp32 -> bf16 conversion (up to 4 equal-size tensors) ----------------
__global__ void cvt_bf16(const float* __restrict__ s0, const float* __restrict__ s1,
                         const float* __restrict__ s2, const float* __restrict__ s3,
                         u16* __restrict__ d0, u16* __restrict__ d1,
                         u16* __restrict__ d2, u16* __restrict__ d3, int n4) {
  const float* srcs[4] = {s0, s1, s2, s3};
  u16* dsts[4] = {d0, d1, d2, d3};
  const float4* src = (const float4*)srcs[blockIdx.y];
  u16* dst = dsts[blockIdx.y];
  for (int i = blockIdx.x * blockDim.x + threadIdx.x; i < n4; i += gridDim.x * blockDim.x) {
    float4 v = src[i];
    ushort4 o;
    o.x = f2bf(v.x); o.y = f2bf(v.y); o.z = f2bf(v.z); o.w = f2bf(v.w);
    *(ushort4*)(dst + (size_t)i * 4) = o;
  }
}

// ---------------- GEMM: C[m][n] = sum_k A[m][k] * Bw[n][k]  (both bf16 row-major, K inner) ----
// MODE 0: C fp32 plain [M][N]
// MODE 1: C bf16 head-split [b*16+h][s][dk]   (m=b*2048+s, n=h*64+dk)
// MODE 2: C bf16 head-split transposed [b*16+h][dk][s]
template<int MODE>
__global__ __launch_bounds__(256)
void gemm_bt(const u16* __restrict__ A, const u16* __restrict__ Bw, void* __restrict__ Cout) {
  constexpr int N = 1024, K = 1024, BK = 64;
  __shared__ u16 As[128 * BK];   // linear [128][64] bf16, 16 KB
  __shared__ u16 Bs[128 * BK];
  const int tid = threadIdx.x;
  const int lane = tid & 63, wave = tid >> 6;
  const int wm = wave >> 1, wn = wave & 1;        // 2x2 wave grid, each 64x64 out
  const int l15 = lane & 15, lhi = lane >> 4;
  const int m0 = blockIdx.y * 128, n0 = blockIdx.x * 128;
  const int r0 = tid >> 3;          // staging row within 32-row stripe
  const int o8 = (tid & 7) * 8;     // staging col (elements)

  f32x4 acc[4][4] = {};

  for (int kt = 0; kt < K / BK; ++kt) {
    const int kb = kt * BK;
#pragma unroll
    for (int c = 0; c < 4; ++c) {
      const int row = c * 32 + r0;
      gload_lds16(A + (m0 + row) * K + kb + o8, (char*)As + (c * 256 + tid) * 16);
      gload_lds16(Bw + (n0 + row) * K + kb + o8, (char*)Bs + (c * 256 + tid) * 16);
    }
    __syncthreads();
#pragma unroll
    for (int kk = 0; kk < 2; ++kk) {
      bf16x8 a[4], b[4];
#pragma unroll
      for (int i = 0; i < 4; ++i)
        a[i] = *(const bf16x8*)(As + (wm * 64 + i * 16 + l15) * BK + kk * 32 + lhi * 8);
#pragma unroll
      for (int j = 0; j < 4; ++j)
        b[j] = *(const bf16x8*)(Bs + (wn * 64 + j * 16 + l15) * BK + kk * 32 + lhi * 8);
#pragma unroll
      for (int i = 0; i < 4; ++i)
#pragma unroll
        for (int j = 0; j < 4; ++j)
          acc[i][j] = __builtin_amdgcn_mfma_f32_16x16x32_bf16(a[i], b[j], acc[i][j], 0, 0, 0);
    }
    __syncthreads();
  }

#pragma unroll
  for (int i = 0; i < 4; ++i) {
#pragma unroll
    for (int j = 0; j < 4; ++j) {
#pragma unroll
      for (int r = 0; r < 4; ++r) {
        const int mg = m0 + wm * 64 + i * 16 + lhi * 4 + r;   // C/D: row=(lane>>4)*4+reg
        const int ng = n0 + wn * 64 + j * 16 + l15;           //      col=lane&15
        const float v = acc[i][j][r];
        if (MODE == 0) {
          ((float*)Cout)[(size_t)mg * N + ng] = v;
        } else {
          const int b = mg >> 11, s = mg & 2047, h = ng >> 6, dk = ng & 63;
          if (MODE == 1)
            ((u16*)Cout)[(((size_t)(b * 16 + h) * 2048 + s) << 6) + dk] = f2bf(v);
          else
            ((u16*)Cout)[((size_t)(b * 16 + h) * 64 + dk) * 2048 + s] = f2bf(v);
        }
      }
    }
  }
}

// ---------------- causal flash attention ----------------
// Q,Kh: [bh][s][64] bf16.  Vt: [bh][64][s] bf16 (transposed).  Ao: [b][s][h][64] bf16.
// Block: 256 thr = 4 waves; each wave owns 16 q-rows; block tile = 64 q-rows.
__global__ __launch_bounds__(256)
void attn_fwd(const u16* __restrict__ Q, const u16* __restrict__ Kh,
              const u16* __restrict__ Vt, u16* __restrict__ Ao) {
  constexpr int S = 2048;
  __shared__ u16 Ks[64 * 64];      // [s_k][d] swizzled: byte ^ ((row&7)<<4)
  __shared__ u16 Vs[64 * 64];      // [d][s_k] swizzled
  __shared__ u16 Ps[4][16 * 64];   // per-wave P tile [q][s_k] swizzled
  const int tid = threadIdx.x;
  const int lane = tid & 63, w = tid >> 6;
  const int l15 = lane & 15, lhi = lane >> 4;
  const int qt = (int)gridDim.x - 1 - (int)blockIdx.x;   // big tiles first
  const int bh = blockIdx.y;

  // Q fragment (A-operand): row=lane&15, k=(lane>>4)*8+j
  const int qrow = qt * 64 + w * 16 + l15;
  const u16* Qb = Q + ((size_t)bh * S + qrow) * 64;
  bf16x8 qf0 = *(const bf16x8*)(Qb + lhi * 8);
  bf16x8 qf1 = *(const bf16x8*)(Qb + 32 + lhi * 8);

  f32x4 o_acc[4] = {};
  float mrow[4] = {-1e30f, -1e30f, -1e30f, -1e30f};
  float lrow[4] = {0.f, 0.f, 0.f, 0.f};

  const int r0 = tid >> 3;          // staging row in 32-row stripe
  const int o16 = (tid & 7) * 16;   // staging byte offset in 128B row
  char* KsB = (char*)Ks;
  char* VsB = (char*)Vs;
  char* PsB = (char*)(Ps[w]);

  for (int kt = 0; kt <= qt; ++kt) {
    // stage K and V^T tiles; LDS linear dest + inverse-swizzled global source (m173)
#pragma unroll
    for (int c = 0; c < 2; ++c) {
      const int row = c * 32 + r0;
      const int gcb = o16 ^ ((row & 7) << 4);
      gload_lds16((const char*)Kh + ((size_t)(bh * S + kt * 64 + row) * 64) * 2 + gcb,
                  KsB + (c * 256 + tid) * 16);
      gload_lds16((const char*)Vt + ((size_t)(bh * 64 + row) * S + kt * 64) * 2 + gcb,
                  VsB + (c * 256 + tid) * 16);
    }
    __syncthreads();

    // S = Q K^T : B-operand col = s_k (K row), k = d
    f32x4 sA[4];
#pragma unroll
    for (int c = 0; c < 4; ++c) {
      f32x4 z = {};
      const int krow = c * 16 + l15;
      const int swz = (krow & 7) << 4;
      z = __builtin_amdgcn_mfma_f32_16x16x32_bf16(
          qf0, *(const bf16x8*)(KsB + ((krow * 128 + lhi * 16) ^ swz)), z, 0, 0, 0);
      z = __builtin_amdgcn_mfma_f32_16x16x32_bf16(
          qf1, *(const bf16x8*)(KsB + ((krow * 128 + 64 + lhi * 16) ^ swz)), z, 0, 0, 0);
      sA[c] = z;
    }

    // scale + causal mask (only diagonal tile is partial)
    const bool diag = (kt == qt);
#pragma unroll
    for (int c = 0; c < 4; ++c)
#pragma unroll
      for (int r = 0; r < 4; ++r) {
        float sv = sA[c][r] * 0.125f;   // 1/sqrt(64)
        if (diag && (c * 16 + l15 > w * 16 + lhi * 4 + r)) sv = -1e30f;
        sA[c][r] = sv;
      }

    // online softmax; S row r lives across the 16 lanes of this lane-group
#pragma unroll
    for (int r = 0; r < 4; ++r) {
      float tm = fmaxf(fmaxf(sA[0][r], sA[1][r]), fmaxf(sA[2][r], sA[3][r]));
      tm = fmaxf(tm, __shfl_xor(tm, 1));
      tm = fmaxf(tm, __shfl_xor(tm, 2));
      tm = fmaxf(tm, __shfl_xor(tm, 4));
      tm = fmaxf(tm, __shfl_xor(tm, 8));
      const float mnew = fmaxf(mrow[r], tm);
      const float sc = __expf(mrow[r] - mnew);
      float rs = 0.f;
#pragma unroll
      for (int c = 0; c < 4; ++c) {
        const float p = __expf(sA[c][r] - mnew);
        sA[c][r] = p;
        rs += p;
      }
      rs += __shfl_xor(rs, 1);
      rs += __shfl_xor(rs, 2);
      rs += __shfl_xor(rs, 4);
      rs += __shfl_xor(rs, 8);
      lrow[r] = lrow[r] * sc + rs;
      mrow[r] = mnew;
#pragma unroll
      for (int c = 0; c < 4; ++c) o_acc[c][r] *= sc;
    }

    // P -> LDS (bf16, swizzled), then read back as PV A-operand
#pragma unroll
    for (int c = 0; c < 4; ++c)
#pragma unroll
      for (int r = 0; r < 4; ++r) {
        const int prow = lhi * 4 + r;
        *(u16*)(PsB + ((prow * 128 + (c * 16 + l15) * 2) ^ ((prow & 7) << 4))) = f2bf(sA[c][r]);
      }

    bf16x8 pa0 = *(const bf16x8*)(PsB + ((l15 * 128 + lhi * 16) ^ ((l15 & 7) << 4)));
    bf16x8 pa1 = *(const bf16x8*)(PsB + ((l15 * 128 + 64 + lhi * 16) ^ ((l15 & 7) << 4)));
#pragma unroll
    for (int c = 0; c < 4; ++c) {
      const int drow = c * 16 + l15;
      const int swz = (drow & 7) << 4;
      o_acc[c] = __builtin_amdgcn_mfma_f32_16x16x32_bf16(
          pa0, *(const bf16x8*)(VsB + ((drow * 128 + lhi * 16) ^ swz)), o_acc[c], 0, 0, 0);
      o_acc[c] = __builtin_amdgcn_mfma_f32_16x16x32_bf16(
          pa1, *(const bf16x8*)(VsB + ((drow * 128 + 64 + lhi * 16) ^ swz)), o_acc[c], 0, 0, 0);
    }
    __syncthreads();
  }

  // epilogue: O / l, write attn out as [b][s][h*64+dk] bf16
  const int b = bh >> 4, h = bh & 15;
#pragma unroll
  for (int r = 0; r < 4; ++r) {
    const float inv = 1.0f / lrow[r];
    const int sg = qt * 64 + w * 16 + lhi * 4 + r;
#pragma unroll
    for (int c = 0; c < 4; ++c)
      Ao[(((size_t)(b * 2048 + sg) * 16 + h) << 6) + c * 16 + l15] = f2bf(o_acc[c][r] * inv);
  }
}

extern "C" void kernel_launch(void* const* d_in, const int* in_sizes, int n_in,
                              void* d_out, int out_size, void* d_ws, size_t ws_size,
                              hipStream_t stream) {
  const float* q  = (const float*)d_in[0];
  const float* k  = (const float*)d_in[1];
  const float* v  = (const float*)d_in[2];
  // d_in[3] = causal mask (triu k=1) -- structurally known, unused
  const float* wq = (const float*)d_in[4];
  const float* wk = (const float*)d_in[5];
  const float* wv = (const float*)d_in[6];
  const float* wo = (const float*)d_in[7];

  char* ws = (char*)d_ws;
  const size_t SZX = (size_t)8192 * 1024 * 2;   // 16 MB bf16 activation
  const size_t SZW = (size_t)1024 * 1024 * 2;   // 2 MB bf16 weight
  u16* Xq = (u16*)(ws);                         // dead after Q-proj GEMM
  u16* Xk = (u16*)(ws + SZX);
  u16* Xv = (u16*)(ws + 2 * SZX);
  u16* Wq = (u16*)(ws + 3 * SZX);
  u16* Wk = (u16*)(ws + 3 * SZX + SZW);
  u16* Wv = (u16*)(ws + 3 * SZX + 2 * SZW);
  u16* Wo = (u16*)(ws + 3 * SZX + 3 * SZW);
  u16* Qh = (u16*)(ws + 3 * SZX + 4 * SZW);
  u16* Kh = (u16*)(ws + 4 * SZX + 4 * SZW);
  u16* Vt = (u16*)(ws + 5 * SZX + 4 * SZW);
  u16* Ao = Xq;                                  // reuse: Ao written only after Xq is dead
  // peak ws use: 6*16MB + 8MB = ~104 MB

  cvt_bf16<<<dim3(1024, 3), 256, 0, stream>>>(q, k, v, q, Xq, Xk, Xv, Xq, 8388608 / 4);
  cvt_bf16<<<dim3(256, 4), 256, 0, stream>>>(wq, wk, wv, wo, Wq, Wk, Wv, Wo, 1048576 / 4);
  gemm_bt<1><<<dim3(8, 64), 256, 0, stream>>>(Xq, Wq, Qh);
  gemm_bt<1><<<dim3(8, 64), 256, 0, stream>>>(Xk, Wk, Kh);
  gemm_bt<2><<<dim3(8, 64), 256, 0, stream>>>(Xv, Wv, Vt);
  attn_fwd<<<dim3(32, 64), 256, 0, stream>>>(Qh, Kh, Vt, Ao);
  gemm_bt<0><<<dim3(8, 64), 256, 0, stream>>>(Ao, Wo, (float*)d_out);
}

// Round 5
// 479.520 us; speedup vs baseline: 1.0430x; 1.0430x over previous
//
#include <hip/hip_runtime.h>

typedef unsigned short u16;
typedef __bf16 bf16x8 __attribute__((ext_vector_type(8)));
typedef float f32x4 __attribute__((ext_vector_type(4)));

__device__ __forceinline__ u16 f2bf(float f) {
  union { float f; unsigned u; } v; v.f = f;
  unsigned r = v.u + 0x7fffu + ((v.u >> 16) & 1u);
  return (u16)(r >> 16);
}

__device__ __forceinline__ void gload_lds16(const void* g, void* l) {
  using gvp = const __attribute__((address_space(1))) void*;
  using lvp = __attribute__((address_space(3))) void*;
  __builtin_amdgcn_global_load_lds((gvp)g, (lvp)l, 16, 0, 0);
}

// ---------------- fp32 -> bf16 conversion (up to 4 equal-size tensors) ----------------
__global__ void cvt_bf16(const float* __restrict__ s0, const float* __restrict__ s1,
                         const float* __restrict__ s2, const float* __restrict__ s3,
                         u16* __restrict__ d0, u16* __restrict__ d1,
                         u16* __restrict__ d2, u16* __restrict__ d3, int n4) {
  const float* srcs[4] = {s0, s1, s2, s3};
  u16* dsts[4] = {d0, d1, d2, d3};
  const float4* src = (const float4*)srcs[blockIdx.y];
  u16* dst = dsts[blockIdx.y];
  for (int i = blockIdx.x * blockDim.x + threadIdx.x; i < n4; i += gridDim.x * blockDim.x) {
    float4 v = src[i];
    ushort4 o;
    o.x = f2bf(v.x); o.y = f2bf(v.y); o.z = f2bf(v.z); o.w = f2bf(v.w);
    *(ushort4*)(dst + (size_t)i * 4) = o;
  }
}

// ---------------- GEMM: C[m][n] = sum_k A[m][k] * Bw[n][k]  (both bf16 row-major, K inner) ----
// MODE 0: C fp32 plain [M][N]
// MODE 1: C bf16 head-split [b*16+h][s][dk]   (m=b*2048+s, n=h*64+dk)
// MODE 2: C bf16 head-split transposed [b*16+h][dk][s]
template<int MODE>
__global__ __launch_bounds__(256)
void gemm_bt(const u16* __restrict__ A, const u16* __restrict__ Bw, void* __restrict__ Cout) {
  constexpr int N = 1024, K = 1024, BK = 64;
  __shared__ u16 As[128 * BK];   // linear [128][64] bf16, 16 KB
  __shared__ u16 Bs[128 * BK];
  const int tid = threadIdx.x;
  const int lane = tid & 63, wave = tid >> 6;
  const int wm = wave >> 1, wn = wave & 1;        // 2x2 wave grid, each 64x64 out
  const int l15 = lane & 15, lhi = lane >> 4;
  const int m0 = blockIdx.y * 128, n0 = blockIdx.x * 128;
  const int r0 = tid >> 3;          // staging row within 32-row stripe
  const int o8 = (tid & 7) * 8;     // staging col (elements)

  f32x4 acc[4][4] = {};

  for (int kt = 0; kt < K / BK; ++kt) {
    const int kb = kt * BK;
#pragma unroll
    for (int c = 0; c < 4; ++c) {
      const int row = c * 32 + r0;
      gload_lds16(A + (m0 + row) * K + kb + o8, (char*)As + (c * 256 + tid) * 16);
      gload_lds16(Bw + (n0 + row) * K + kb + o8, (char*)Bs + (c * 256 + tid) * 16);
    }
    __syncthreads();
#pragma unroll
    for (int kk = 0; kk < 2; ++kk) {
      bf16x8 a[4], b[4];
#pragma unroll
      for (int i = 0; i < 4; ++i)
        a[i] = *(const bf16x8*)(As + (wm * 64 + i * 16 + l15) * BK + kk * 32 + lhi * 8);
#pragma unroll
      for (int j = 0; j < 4; ++j)
        b[j] = *(const bf16x8*)(Bs + (wn * 64 + j * 16 + l15) * BK + kk * 32 + lhi * 8);
#pragma unroll
      for (int i = 0; i < 4; ++i)
#pragma unroll
        for (int j = 0; j < 4; ++j)
          acc[i][j] = __builtin_amdgcn_mfma_f32_16x16x32_bf16(a[i], b[j], acc[i][j], 0, 0, 0);
    }
    __syncthreads();
  }

#pragma unroll
  for (int i = 0; i < 4; ++i) {
#pragma unroll
    for (int j = 0; j < 4; ++j) {
#pragma unroll
      for (int r = 0; r < 4; ++r) {
        const int mg = m0 + wm * 64 + i * 16 + lhi * 4 + r;   // C/D: row=(lane>>4)*4+reg
        const int ng = n0 + wn * 64 + j * 16 + l15;           //      col=lane&15
        const float v = acc[i][j][r];
        if (MODE == 0) {
          ((float*)Cout)[(size_t)mg * N + ng] = v;
        } else {
          const int b = mg >> 11, s = mg & 2047, h = ng >> 6, dk = ng & 63;
          if (MODE == 1)
            ((u16*)Cout)[(((size_t)(b * 16 + h) * 2048 + s) << 6) + dk] = f2bf(v);
          else
            ((u16*)Cout)[((size_t)(b * 16 + h) * 64 + dk) * 2048 + s] = f2bf(v);
        }
      }
    }
  }
}

// ---------------- causal flash attention (double-buffered, 1 barrier/tile) ----------------
// Q,Kh: [bh][s][64] bf16.  Vt: [bh][64][s] bf16 (transposed).  Ao: [b][s][h][64] bf16.
// Block: 256 thr = 4 waves; each wave owns 16 q-rows; block tile = 64 q-rows.
__global__ __launch_bounds__(256)
void attn_fwd(const u16* __restrict__ Q, const u16* __restrict__ Kh,
              const u16* __restrict__ Vt, u16* __restrict__ Ao) {
  constexpr int S = 2048;
  __shared__ u16 Ks[2][64 * 64];   // [buf][s_k][d] swizzled: byte ^ ((row&7)<<4)
  __shared__ u16 Vs[2][64 * 64];   // [buf][d][s_k] swizzled
  __shared__ u16 Ps[4][16 * 64];   // per-wave P tile [q][s_k] swizzled
  const int tid = threadIdx.x;
  const int lane = tid & 63, w = tid >> 6;
  const int l15 = lane & 15, lhi = lane >> 4;
  const int qt = (int)gridDim.x - 1 - (int)blockIdx.x;   // big tiles first
  const int bh = blockIdx.y;

  // Q fragment (A-operand): row=lane&15, k=(lane>>4)*8+j
  const int qrow = qt * 64 + w * 16 + l15;
  const u16* Qb = Q + ((size_t)bh * S + qrow) * 64;
  bf16x8 qf0 = *(const bf16x8*)(Qb + lhi * 8);
  bf16x8 qf1 = *(const bf16x8*)(Qb + 32 + lhi * 8);

  f32x4 o_acc[4] = {};
  float mrow[4] = {-1e30f, -1e30f, -1e30f, -1e30f};
  float lrow[4] = {0.f, 0.f, 0.f, 0.f};

  const int r0 = tid >> 3;          // staging row in 32-row stripe
  const int o16 = (tid & 7) * 16;   // staging byte offset in 128B row
  char* PsB = (char*)(Ps[w]);

  // stage tile kt into buffer b: LDS linear dest + inverse-swizzled global src (m173)
  auto STAGE = [&](int b, int kt) {
#pragma unroll
    for (int c = 0; c < 2; ++c) {
      const int row = c * 32 + r0;
      const int gcb = o16 ^ ((row & 7) << 4);
      gload_lds16((const char*)Kh + ((size_t)(bh * S + kt * 64 + row) * 64) * 2 + gcb,
                  (char*)(Ks[b]) + (c * 256 + tid) * 16);
      gload_lds16((const char*)Vt + ((size_t)(bh * 64 + row) * S + kt * 64) * 2 + gcb,
                  (char*)(Vs[b]) + (c * 256 + tid) * 16);
    }
  };

  STAGE(0, 0);
  __syncthreads();                   // full drain: buf0 ready
  int buf = 0;

  for (int kt = 0; kt <= qt; ++kt) {
    // issue next tile's loads first; they fly while we compute this tile (T3 2-phase)
    if (kt < qt) STAGE(buf ^ 1, kt + 1);

    const char* KsB = (const char*)(Ks[buf]);
    const char* VsB = (const char*)(Vs[buf]);

    // S = Q K^T : B-operand col = s_k (K row), k = d
    f32x4 sA[4];
    __builtin_amdgcn_s_setprio(1);
#pragma unroll
    for (int c = 0; c < 4; ++c) {
      f32x4 z = {};
      const int krow = c * 16 + l15;
      const int swz = (krow & 7) << 4;
      z = __builtin_amdgcn_mfma_f32_16x16x32_bf16(
          qf0, *(const bf16x8*)(KsB + ((krow * 128 + lhi * 16) ^ swz)), z, 0, 0, 0);
      z = __builtin_amdgcn_mfma_f32_16x16x32_bf16(
          qf1, *(const bf16x8*)(KsB + ((krow * 128 + 64 + lhi * 16) ^ swz)), z, 0, 0, 0);
      sA[c] = z;
    }
    __builtin_amdgcn_s_setprio(0);

    // scale + causal mask (only diagonal tile is partial)
    const bool diag = (kt == qt);
#pragma unroll
    for (int c = 0; c < 4; ++c)
#pragma unroll
      for (int r = 0; r < 4; ++r) {
        float sv = sA[c][r] * 0.125f;   // 1/sqrt(64)
        if (diag && (c * 16 + l15 > w * 16 + lhi * 4 + r)) sv = -1e30f;
        sA[c][r] = sv;
      }

    // online softmax; S row r lives across the 16 lanes of this lane-group
#pragma unroll
    for (int r = 0; r < 4; ++r) {
      float tm = fmaxf(fmaxf(sA[0][r], sA[1][r]), fmaxf(sA[2][r], sA[3][r]));
      tm = fmaxf(tm, __shfl_xor(tm, 1));
      tm = fmaxf(tm, __shfl_xor(tm, 2));
      tm = fmaxf(tm, __shfl_xor(tm, 4));
      tm = fmaxf(tm, __shfl_xor(tm, 8));
      const float mnew = fmaxf(mrow[r], tm);
      const float sc = __expf(mrow[r] - mnew);
      float rs = 0.f;
#pragma unroll
      for (int c = 0; c < 4; ++c) {
        const float p = __expf(sA[c][r] - mnew);
        sA[c][r] = p;
        rs += p;
      }
      rs += __shfl_xor(rs, 1);
      rs += __shfl_xor(rs, 2);
      rs += __shfl_xor(rs, 4);
      rs += __shfl_xor(rs, 8);
      lrow[r] = lrow[r] * sc + rs;
      mrow[r] = mnew;
#pragma unroll
      for (int c = 0; c < 4; ++c) o_acc[c][r] *= sc;
    }

    // P -> LDS (bf16, swizzled), then read back as PV A-operand (same-wave, lgkmcnt-ordered)
#pragma unroll
    for (int c = 0; c < 4; ++c)
#pragma unroll
      for (int r = 0; r < 4; ++r) {
        const int prow = lhi * 4 + r;
        *(u16*)(PsB + ((prow * 128 + (c * 16 + l15) * 2) ^ ((prow & 7) << 4))) = f2bf(sA[c][r]);
      }

    bf16x8 pa0 = *(const bf16x8*)(PsB + ((l15 * 128 + lhi * 16) ^ ((l15 & 7) << 4)));
    bf16x8 pa1 = *(const bf16x8*)(PsB + ((l15 * 128 + 64 + lhi * 16) ^ ((l15 & 7) << 4)));
    __builtin_amdgcn_s_setprio(1);
#pragma unroll
    for (int c = 0; c < 4; ++c) {
      const int drow = c * 16 + l15;
      const int swz = (drow & 7) << 4;
      o_acc[c] = __builtin_amdgcn_mfma_f32_16x16x32_bf16(
          pa0, *(const bf16x8*)(VsB + ((drow * 128 + lhi * 16) ^ swz)), o_acc[c], 0, 0, 0);
      o_acc[c] = __builtin_amdgcn_mfma_f32_16x16x32_bf16(
          pa1, *(const bf16x8*)(VsB + ((drow * 128 + 64 + lhi * 16) ^ swz)), o_acc[c], 0, 0, 0);
    }
    __builtin_amdgcn_s_setprio(0);

    __syncthreads();   // drains vmcnt(0): next buf staged + all waves done reading this buf
    buf ^= 1;
  }

  // epilogue: O / l, write attn out as [b][s][h*64+dk] bf16
  const int b = bh >> 4, h = bh & 15;
#pragma unroll
  for (int r = 0; r < 4; ++r) {
    const float inv = 1.0f / lrow[r];
    const int sg = qt * 64 + w * 16 + lhi * 4 + r;
#pragma unroll
    for (int c = 0; c < 4; ++c)
      Ao[(((size_t)(b * 2048 + sg) * 16 + h) << 6) + c * 16 + l15] = f2bf(o_acc[c][r] * inv);
  }
}

extern "C" void kernel_launch(void* const* d_in, const int* in_sizes, int n_in,
                              void* d_out, int out_size, void* d_ws, size_t ws_size,
                              hipStream_t stream) {
  const float* q  = (const float*)d_in[0];
  const float* k  = (const float*)d_in[1];
  const float* v  = (const float*)d_in[2];
  // d_in[3] = causal mask (triu k=1) -- structurally known, unused
  const float* wq = (const float*)d_in[4];
  const float* wk = (const float*)d_in[5];
  const float* wv = (const float*)d_in[6];
  const float* wo = (const float*)d_in[7];

  char* ws = (char*)d_ws;
  const size_t SZX = (size_t)8192 * 1024 * 2;   // 16 MB bf16 activation
  const size_t SZW = (size_t)1024 * 1024 * 2;   // 2 MB bf16 weight
  u16* Xq = (u16*)(ws);                         // dead after Q-proj GEMM
  u16* Xk = (u16*)(ws + SZX);
  u16* Xv = (u16*)(ws + 2 * SZX);
  u16* Wq = (u16*)(ws + 3 * SZX);
  u16* Wk = (u16*)(ws + 3 * SZX + SZW);
  u16* Wv = (u16*)(ws + 3 * SZX + 2 * SZW);
  u16* Wo = (u16*)(ws + 3 * SZX + 3 * SZW);
  u16* Qh = (u16*)(ws + 3 * SZX + 4 * SZW);
  u16* Kh = (u16*)(ws + 4 * SZX + 4 * SZW);
  u16* Vt = (u16*)(ws + 5 * SZX + 4 * SZW);
  u16* Ao = Xq;                                  // reuse: Ao written only after Xq is dead
  // peak ws use: 6*16MB + 8MB = ~104 MB

  cvt_bf16<<<dim3(1024, 3), 256, 0, stream>>>(q, k, v, q, Xq, Xk, Xv, Xq, 8388608 / 4);
  cvt_bf16<<<dim3(256, 4), 256, 0, stream>>>(wq, wk, wv, wo, Wq, Wk, Wv, Wo, 1048576 / 4);
  gemm_bt<1><<<dim3(8, 64), 256, 0, stream>>>(Xq, Wq, Qh);
  gemm_bt<1><<<dim3(8, 64), 256, 0, stream>>>(Xk, Wk, Kh);
  gemm_bt<2><<<dim3(8, 64), 256, 0, stream>>>(Xv, Wv, Vt);
  attn_fwd<<<dim3(32, 64), 256, 0, stream>>>(Qh, Kh, Vt, Ao);
  gemm_bt<0><<<dim3(8, 64), 256, 0, stream>>>(Ao, Wo, (float*)d_out);
}

// Round 8
// 473.074 us; speedup vs baseline: 1.0572x; 1.0136x over previous
//
#include <hip/hip_runtime.h>

typedef unsigned short u16;
typedef __bf16 bf16x8 __attribute__((ext_vector_type(8)));
typedef float f32x4 __attribute__((ext_vector_type(4)));

__device__ __forceinline__ u16 f2bf(float f) {
  union { float f; unsigned u; } v; v.f = f;
  unsigned r = v.u + 0x7fffu + ((v.u >> 16) & 1u);
  return (u16)(r >> 16);
}

// native cast form: numerically identical (RNE), lets compiler pack v_cvt_pk_bf16_f32
__device__ __forceinline__ u16 f2bfn(float f) {
  union { __bf16 h; u16 u; } v; v.h = (__bf16)f; return v.u;
}

__device__ __forceinline__ void gload_lds16(const void* g, void* l) {
  using gvp = const __attribute__((address_space(1))) void*;
  using lvp = __attribute__((address_space(3))) void*;
  __builtin_amdgcn_global_load_lds((gvp)g, (lvp)l, 16, 0, 0);
}

// ---------------- fp32 -> bf16 conversion (up to 4 equal-size tensors) ----------------
__global__ void cvt_bf16(const float* __restrict__ s0, const float* __restrict__ s1,
                         const float* __restrict__ s2, const float* __restrict__ s3,
                         u16* __restrict__ d0, u16* __restrict__ d1,
                         u16* __restrict__ d2, u16* __restrict__ d3, int n4) {
  const float* srcs[4] = {s0, s1, s2, s3};
  u16* dsts[4] = {d0, d1, d2, d3};
  const float4* src = (const float4*)srcs[blockIdx.y];
  u16* dst = dsts[blockIdx.y];
  for (int i = blockIdx.x * blockDim.x + threadIdx.x; i < n4; i += gridDim.x * blockDim.x) {
    float4 v = src[i];
    ushort4 o;
    o.x = f2bf(v.x); o.y = f2bf(v.y); o.z = f2bf(v.z); o.w = f2bf(v.w);
    *(ushort4*)(dst + (size_t)i * 4) = o;
  }
}

// ---------------- GEMM: C[m][n] = sum_k A[m][k] * Bw[n][k]  (both bf16 row-major, K inner) ----
// MODE 0: C fp32 plain [M][N]
// MODE 1: C bf16 head-split [b*16+h][s][dk]   (m=b*2048+s, n=h*64+dk)
// MODE 2: C bf16 head-split transposed [b*16+h][dk][s]
template<int MODE>
__global__ __launch_bounds__(256)
void gemm_bt(const u16* __restrict__ A, const u16* __restrict__ Bw, void* __restrict__ Cout) {
  constexpr int N = 1024, K = 1024, BK = 64;
  __shared__ u16 As[128 * BK];   // linear [128][64] bf16, 16 KB
  __shared__ u16 Bs[128 * BK];
  const int tid = threadIdx.x;
  const int lane = tid & 63, wave = tid >> 6;
  const int wm = wave >> 1, wn = wave & 1;        // 2x2 wave grid, each 64x64 out
  const int l15 = lane & 15, lhi = lane >> 4;
  const int m0 = blockIdx.y * 128, n0 = blockIdx.x * 128;
  const int r0 = tid >> 3;          // staging row within 32-row stripe
  const int o8 = (tid & 7) * 8;     // staging col (elements)

  f32x4 acc[4][4] = {};

  for (int kt = 0; kt < K / BK; ++kt) {
    const int kb = kt * BK;
#pragma unroll
    for (int c = 0; c < 4; ++c) {
      const int row = c * 32 + r0;
      gload_lds16(A + (m0 + row) * K + kb + o8, (char*)As + (c * 256 + tid) * 16);
      gload_lds16(Bw + (n0 + row) * K + kb + o8, (char*)Bs + (c * 256 + tid) * 16);
    }
    __syncthreads();
#pragma unroll
    for (int kk = 0; kk < 2; ++kk) {
      bf16x8 a[4], b[4];
#pragma unroll
      for (int i = 0; i < 4; ++i)
        a[i] = *(const bf16x8*)(As + (wm * 64 + i * 16 + l15) * BK + kk * 32 + lhi * 8);
#pragma unroll
      for (int j = 0; j < 4; ++j)
        b[j] = *(const bf16x8*)(Bs + (wn * 64 + j * 16 + l15) * BK + kk * 32 + lhi * 8);
#pragma unroll
      for (int i = 0; i < 4; ++i)
#pragma unroll
        for (int j = 0; j < 4; ++j)
          acc[i][j] = __builtin_amdgcn_mfma_f32_16x16x32_bf16(a[i], b[j], acc[i][j], 0, 0, 0);
    }
    __syncthreads();
  }

#pragma unroll
  for (int i = 0; i < 4; ++i) {
#pragma unroll
    for (int j = 0; j < 4; ++j) {
#pragma unroll
      for (int r = 0; r < 4; ++r) {
        const int mg = m0 + wm * 64 + i * 16 + lhi * 4 + r;   // C/D: row=(lane>>4)*4+reg
        const int ng = n0 + wn * 64 + j * 16 + l15;           //      col=lane&15
        const float v = acc[i][j][r];
        if (MODE == 0) {
          ((float*)Cout)[(size_t)mg * N + ng] = v;
        } else {
          const int b = mg >> 11, s = mg & 2047, h = ng >> 6, dk = ng & 63;
          if (MODE == 1)
            ((u16*)Cout)[(((size_t)(b * 16 + h) * 2048 + s) << 6) + dk] = f2bf(v);
          else
            ((u16*)Cout)[((size_t)(b * 16 + h) * 64 + dk) * 2048 + s] = f2bf(v);
        }
      }
    }
  }
}

// ---------------- causal flash attention (8 waves, 128 q-rows/block, dbuf, 1 barrier/tile) ----
// Q,Kh: [bh][s][64] bf16.  Vt: [bh][64][s] bf16 (transposed).  Ao: [b][s][h][64] bf16.
// Block: 512 thr = 8 waves; each wave owns 16 q-rows; block tile = 128 q-rows.
__global__ __launch_bounds__(512)
void attn_fwd(const u16* __restrict__ Q, const u16* __restrict__ Kh,
              const u16* __restrict__ Vt, u16* __restrict__ Ao) {
  constexpr int S = 2048;
  constexpr float SCL = 0.125f * 1.44269504088896f;   // (1/sqrt(64)) * log2(e)
  __shared__ u16 Ks[2][64 * 64];   // [buf][s_k][d] swizzled: byte ^ ((row&7)<<4)
  __shared__ u16 Vs[2][64 * 64];   // [buf][d][s_k] swizzled
  __shared__ u16 Ps[8][16 * 64];   // per-wave P tile [q][s_k] swizzled
  const int tid = threadIdx.x;
  const int lane = tid & 63, w = tid >> 6;               // 8 waves
  const int l15 = lane & 15, lhi = lane >> 4;
  const int qb = (int)gridDim.x - 1 - (int)blockIdx.x;   // big tiles first, 0..15
  const int bh = blockIdx.y;

  // Q fragment (A-operand): row=lane&15, k=(lane>>4)*8+j
  const int qrow = qb * 128 + w * 16 + l15;
  const u16* Qb = Q + ((size_t)bh * S + qrow) * 64;
  bf16x8 qf0 = *(const bf16x8*)(Qb + lhi * 8);
  bf16x8 qf1 = *(const bf16x8*)(Qb + 32 + lhi * 8);

  f32x4 o_acc[4] = {};
  float mrow[4] = {-1e30f, -1e30f, -1e30f, -1e30f};
  float lrow[4] = {0.f, 0.f, 0.f, 0.f};

  const int srow = tid >> 3;        // staging row 0..63 (512 thr cover 64x128B tile)
  const int o16 = (tid & 7) * 16;   // staging byte offset in 128B row
  const int gcb = o16 ^ ((srow & 7) << 4);   // inverse-swizzled global col (m173)
  char* PsB = (char*)(Ps[w]);

  // stage tile kt into buffer b: LDS linear dest + inverse-swizzled global source
  auto STAGE = [&](int b, int kt) {
    gload_lds16((const char*)Kh + ((size_t)(bh * S + kt * 64 + srow) * 64) * 2 + gcb,
                (char*)(Ks[b]) + tid * 16);
    gload_lds16((const char*)Vt + ((size_t)(bh * 64 + srow) * S + kt * 64) * 2 + gcb,
                (char*)(Vs[b]) + tid * 16);
  };

  const int ktmax = 2 * qb + 1;
  const int qmin_w = qb * 128 + w * 16;        // this wave's first q-row
  const int qmax_w = qmin_w + 15;              // this wave's last q-row

  STAGE(0, 0);
  __syncthreads();                   // full drain: buf0 ready
  int buf = 0;

  for (int kt = 0; kt <= ktmax; ++kt) {
    // issue next tile's loads first; they fly while we compute this tile (T3 2-phase)
    if (kt < ktmax) STAGE(buf ^ 1, kt + 1);

    const bool allmask = kt * 64 > qmax_w;     // tile entirely above diagonal for this wave
    if (!allmask) {
      const char* KsB = (const char*)(Ks[buf]);
      const char* VsB = (const char*)(Vs[buf]);

      // S = Q K^T : B-operand col = s_k (K row), k = d
      f32x4 sA[4];
      __builtin_amdgcn_s_setprio(1);
#pragma unroll
      for (int c = 0; c < 4; ++c) {
        f32x4 z = {};
        const int krow = c * 16 + l15;
        const int swz = (krow & 7) << 4;
        z = __builtin_amdgcn_mfma_f32_16x16x32_bf16(
            qf0, *(const bf16x8*)(KsB + ((krow * 128 + lhi * 16) ^ swz)), z, 0, 0, 0);
        z = __builtin_amdgcn_mfma_f32_16x16x32_bf16(
            qf1, *(const bf16x8*)(KsB + ((krow * 128 + 64 + lhi * 16) ^ swz)), z, 0, 0, 0);
        sA[c] = z;
      }
      __builtin_amdgcn_s_setprio(0);

      // scale (log2-domain) + causal mask.
      // anymask must compare against the wave's FIRST row (any key > any row needs masking);
      // round-7 bug: comparing vs qmax_w left waves 3 & 7's diagonal tiles unmasked.
      const bool anymask = (kt * 64 + 63) > qmin_w;
#pragma unroll
      for (int c = 0; c < 4; ++c)
#pragma unroll
        for (int r = 0; r < 4; ++r) {
          float sv = sA[c][r] * SCL;
          if (anymask && (kt * 64 + c * 16 + l15 > qmin_w + lhi * 4 + r)) sv = -1e30f;
          sA[c][r] = sv;
        }

      // online softmax (base-2); S row r lives across the 16 lanes of this lane-group
#pragma unroll
      for (int r = 0; r < 4; ++r) {
        float tm = fmaxf(fmaxf(sA[0][r], sA[1][r]), fmaxf(sA[2][r], sA[3][r]));
        tm = fmaxf(tm, __shfl_xor(tm, 1));
        tm = fmaxf(tm, __shfl_xor(tm, 2));
        tm = fmaxf(tm, __shfl_xor(tm, 4));
        tm = fmaxf(tm, __shfl_xor(tm, 8));
        const float mnew = fmaxf(mrow[r], tm);
        const float sc = __builtin_amdgcn_exp2f(mrow[r] - mnew);
        float rs = 0.f;
#pragma unroll
        for (int c = 0; c < 4; ++c) {
          const float p = __builtin_amdgcn_exp2f(sA[c][r] - mnew);
          sA[c][r] = p;
          rs += p;
        }
        rs += __shfl_xor(rs, 1);
        rs += __shfl_xor(rs, 2);
        rs += __shfl_xor(rs, 4);
        rs += __shfl_xor(rs, 8);
        lrow[r] = lrow[r] * sc + rs;
        mrow[r] = mnew;
#pragma unroll
        for (int c = 0; c < 4; ++c) o_acc[c][r] *= sc;
      }

      // P -> LDS (bf16, swizzled), then read back as PV A-operand (same-wave, lgkm-ordered)
#pragma unroll
      for (int c = 0; c < 4; ++c)
#pragma unroll
        for (int r = 0; r < 4; ++r) {
          const int prow = lhi * 4 + r;
          *(u16*)(PsB + ((prow * 128 + (c * 16 + l15) * 2) ^ ((prow & 7) << 4))) = f2bfn(sA[c][r]);
        }

      bf16x8 pa0 = *(const bf16x8*)(PsB + ((l15 * 128 + lhi * 16) ^ ((l15 & 7) << 4)));
      bf16x8 pa1 = *(const bf16x8*)(PsB + ((l15 * 128 + 64 + lhi * 16) ^ ((l15 & 7) << 4)));
      __builtin_amdgcn_s_setprio(1);
#pragma unroll
      for (int c = 0; c < 4; ++c) {
        const int drow = c * 16 + l15;
        const int swz = (drow & 7) << 4;
        o_acc[c] = __builtin_amdgcn_mfma_f32_16x16x32_bf16(
            pa0, *(const bf16x8*)(VsB + ((drow * 128 + lhi * 16) ^ swz)), o_acc[c], 0, 0, 0);
        o_acc[c] = __builtin_amdgcn_mfma_f32_16x16x32_bf16(
            pa1, *(const bf16x8*)(VsB + ((drow * 128 + 64 + lhi * 16) ^ swz)), o_acc[c], 0, 0, 0);
      }
      __builtin_amdgcn_s_setprio(0);
    }

    __syncthreads();   // drains vmcnt(0): next buf staged + all waves done with this buf
    buf ^= 1;
  }

  // epilogue: O / l, write attn out as [b][s][h*64+dk] bf16
  const int b = bh >> 4, h = bh & 15;
#pragma unroll
  for (int r = 0; r < 4; ++r) {
    const float inv = 1.0f / lrow[r];
    const int sg = qb * 128 + w * 16 + lhi * 4 + r;
#pragma unroll
    for (int c = 0; c < 4; ++c)
      Ao[(((size_t)(b * 2048 + sg) * 16 + h) << 6) + c * 16 + l15] = f2bfn(o_acc[c][r] * inv);
  }
}

extern "C" void kernel_launch(void* const* d_in, const int* in_sizes, int n_in,
                              void* d_out, int out_size, void* d_ws, size_t ws_size,
                              hipStream_t stream) {
  const float* q  = (const float*)d_in[0];
  const float* k  = (const float*)d_in[1];
  const float* v  = (const float*)d_in[2];
  // d_in[3] = causal mask (triu k=1) -- structurally known, unused
  const float* wq = (const float*)d_in[4];
  const float* wk = (const float*)d_in[5];
  const float* wv = (const float*)d_in[6];
  const float* wo = (const float*)d_in[7];

  char* ws = (char*)d_ws;
  const size_t SZX = (size_t)8192 * 1024 * 2;   // 16 MB bf16 activation
  const size_t SZW = (size_t)1024 * 1024 * 2;   // 2 MB bf16 weight
  u16* Xq = (u16*)(ws);                         // dead after Q-proj GEMM
  u16* Xk = (u16*)(ws + SZX);
  u16* Xv = (u16*)(ws + 2 * SZX);
  u16* Wq = (u16*)(ws + 3 * SZX);
  u16* Wk = (u16*)(ws + 3 * SZX + SZW);
  u16* Wv = (u16*)(ws + 3 * SZX + 2 * SZW);
  u16* Wo = (u16*)(ws + 3 * SZX + 3 * SZW);
  u16* Qh = (u16*)(ws + 3 * SZX + 4 * SZW);
  u16* Kh = (u16*)(ws + 4 * SZX + 4 * SZW);
  u16* Vt = (u16*)(ws + 5 * SZX + 4 * SZW);
  u16* Ao = Xq;                                  // reuse: Ao written only after Xq is dead
  // peak ws use: 6*16MB + 8MB = ~104 MB

  cvt_bf16<<<dim3(1024, 3), 256, 0, stream>>>(q, k, v, q, Xq, Xk, Xv, Xq, 8388608 / 4);
  cvt_bf16<<<dim3(256, 4), 256, 0, stream>>>(wq, wk, wv, wo, Wq, Wk, Wv, Wo, 1048576 / 4);
  gemm_bt<1><<<dim3(8, 64), 256, 0, stream>>>(Xq, Wq, Qh);
  gemm_bt<1><<<dim3(8, 64), 256, 0, stream>>>(Xk, Wk, Kh);
  gemm_bt<2><<<dim3(8, 64), 256, 0, stream>>>(Xv, Wv, Vt);
  attn_fwd<<<dim3(16, 64), 512, 0, stream>>>(Qh, Kh, Vt, Ao);
  gemm_bt<0><<<dim3(8, 64), 256, 0, stream>>>(Ao, Wo, (float*)d_out);
}

// Round 10
// 415.278 us; speedup vs baseline: 1.2043x; 1.1392x over previous
//
#include <hip/hip_runtime.h>

typedef unsigned short u16;
typedef __bf16 bf16x8 __attribute__((ext_vector_type(8)));
typedef float f32x4 __attribute__((ext_vector_type(4)));

__device__ __forceinline__ u16 f2bf(float f) {
  union { float f; unsigned u; } v; v.f = f;
  unsigned r = v.u + 0x7fffu + ((v.u >> 16) & 1u);
  return (u16)(r >> 16);
}

// native cast form: numerically identical (RNE), lets compiler pack v_cvt_pk_bf16_f32
__device__ __forceinline__ u16 f2bfn(float f) {
  union { __bf16 h; u16 u; } v; v.h = (__bf16)f; return v.u;
}

__device__ __forceinline__ void gload_lds16(const void* g, void* l) {
  using gvp = const __attribute__((address_space(1))) void*;
  using lvp = __attribute__((address_space(3))) void*;
  __builtin_amdgcn_global_load_lds((gvp)g, (lvp)l, 16, 0, 0);
}

// ---------------- fp32 -> bf16 conversion (up to 4 equal-size tensors) ----------------
__global__ void cvt_bf16(const float* __restrict__ s0, const float* __restrict__ s1,
                         const float* __restrict__ s2, const float* __restrict__ s3,
                         u16* __restrict__ d0, u16* __restrict__ d1,
                         u16* __restrict__ d2, u16* __restrict__ d3, int n4) {
  const float* srcs[4] = {s0, s1, s2, s3};
  u16* dsts[4] = {d0, d1, d2, d3};
  const float4* src = (const float4*)srcs[blockIdx.y];
  u16* dst = dsts[blockIdx.y];
  for (int i = blockIdx.x * blockDim.x + threadIdx.x; i < n4; i += gridDim.x * blockDim.x) {
    float4 v = src[i];
    ushort4 o;
    o.x = f2bf(v.x); o.y = f2bf(v.y); o.z = f2bf(v.z); o.w = f2bf(v.w);
    *(ushort4*)(dst + (size_t)i * 4) = o;
  }
}

// ---------------- GEMM: C[m][n] = sum_k A[m][k] * Bw[n][k]  (both bf16 row-major, K inner) ----
// MODE 0: C fp32 plain [M][N]
// MODE 1: C bf16 head-split [b*16+h][s][dk]   (m=b*2048+s, n=h*64+dk)
// MODE 2: C bf16 head-split transposed [b*16+h][dk][s]
template<int MODE>
__global__ __launch_bounds__(256)
void gemm_bt(const u16* __restrict__ A, const u16* __restrict__ Bw, void* __restrict__ Cout) {
  constexpr int N = 1024, K = 1024, BK = 64;
  __shared__ u16 As[128 * BK];   // linear [128][64] bf16, 16 KB
  __shared__ u16 Bs[128 * BK];
  const int tid = threadIdx.x;
  const int lane = tid & 63, wave = tid >> 6;
  const int wm = wave >> 1, wn = wave & 1;        // 2x2 wave grid, each 64x64 out
  const int l15 = lane & 15, lhi = lane >> 4;
  const int m0 = blockIdx.y * 128, n0 = blockIdx.x * 128;
  const int r0 = tid >> 3;          // staging row within 32-row stripe
  const int o8 = (tid & 7) * 8;     // staging col (elements)

  f32x4 acc[4][4] = {};

  for (int kt = 0; kt < K / BK; ++kt) {
    const int kb = kt * BK;
#pragma unroll
    for (int c = 0; c < 4; ++c) {
      const int row = c * 32 + r0;
      gload_lds16(A + (m0 + row) * K + kb + o8, (char*)As + (c * 256 + tid) * 16);
      gload_lds16(Bw + (n0 + row) * K + kb + o8, (char*)Bs + (c * 256 + tid) * 16);
    }
    __syncthreads();
#pragma unroll
    for (int kk = 0; kk < 2; ++kk) {
      bf16x8 a[4], b[4];
#pragma unroll
      for (int i = 0; i < 4; ++i)
        a[i] = *(const bf16x8*)(As + (wm * 64 + i * 16 + l15) * BK + kk * 32 + lhi * 8);
#pragma unroll
      for (int j = 0; j < 4; ++j)
        b[j] = *(const bf16x8*)(Bs + (wn * 64 + j * 16 + l15) * BK + kk * 32 + lhi * 8);
#pragma unroll
      for (int i = 0; i < 4; ++i)
#pragma unroll
        for (int j = 0; j < 4; ++j)
          acc[i][j] = __builtin_amdgcn_mfma_f32_16x16x32_bf16(a[i], b[j], acc[i][j], 0, 0, 0);
    }
    __syncthreads();
  }

#pragma unroll
  for (int i = 0; i < 4; ++i) {
#pragma unroll
    for (int j = 0; j < 4; ++j) {
#pragma unroll
      for (int r = 0; r < 4; ++r) {
        const int mg = m0 + wm * 64 + i * 16 + lhi * 4 + r;   // C/D: row=(lane>>4)*4+reg
        const int ng = n0 + wn * 64 + j * 16 + l15;           //      col=lane&15
        const float v = acc[i][j][r];
        if (MODE == 0) {
          ((float*)Cout)[(size_t)mg * N + ng] = v;
        } else {
          const int b = mg >> 11, s = mg & 2047, h = ng >> 6, dk = ng & 63;
          if (MODE == 1)
            ((u16*)Cout)[(((size_t)(b * 16 + h) * 2048 + s) << 6) + dk] = f2bf(v);
          else
            ((u16*)Cout)[((size_t)(b * 16 + h) * 64 + dk) * 2048 + s] = f2bf(v);
        }
      }
    }
  }
}

// ---------------- causal flash attention (paired q-tiles for perfect balance) ----------------
// Q,Kh: [bh][s][64] bf16.  Vt: [bh][64][s] bf16 (transposed).  Ao: [b][s][h][64] bf16.
// Block: 256 thr = 4 waves; each wave owns 16 q-rows; q-tile = 64 rows.
// Each block processes q-tiles (31-x) then (x): constant 33 k-tiles per block.
// Grid 16x64 = 1024 blocks = 4/CU, LDS 40KB = exactly 4 blocks resident -> balanced, no tail.
__global__ __launch_bounds__(256)
void attn_fwd(const u16* __restrict__ Q, const u16* __restrict__ Kh,
              const u16* __restrict__ Vt, u16* __restrict__ Ao) {
  constexpr int S = 2048;
  constexpr float SCL = 0.125f * 1.44269504088896f;   // (1/sqrt(64)) * log2(e)
  __shared__ u16 Ks[2][64 * 64];   // [buf][s_k][d] swizzled: byte ^ ((row&7)<<4)
  __shared__ u16 Vs[2][64 * 64];   // [buf][d][s_k] swizzled
  __shared__ u16 Ps[4][16 * 64];   // per-wave P tile [q][s_k] swizzled
  const int tid = threadIdx.x;
  const int lane = tid & 63, w = tid >> 6;
  const int l15 = lane & 15, lhi = lane >> 4;
  const int bh = blockIdx.y;
  const int qtA = 31 - (int)blockIdx.x;      // big phase first
  const int qtB = (int)blockIdx.x;

  // Q fragments for both phases (A-operand): row=lane&15, k=(lane>>4)*8+j
  const u16* QbA = Q + ((size_t)bh * S + qtA * 64 + w * 16 + l15) * 64;
  const u16* QbB = Q + ((size_t)bh * S + qtB * 64 + w * 16 + l15) * 64;
  const bf16x8 qfA0 = *(const bf16x8*)(QbA + lhi * 8);
  const bf16x8 qfA1 = *(const bf16x8*)(QbA + 32 + lhi * 8);
  const bf16x8 qfB0 = *(const bf16x8*)(QbB + lhi * 8);
  const bf16x8 qfB1 = *(const bf16x8*)(QbB + 32 + lhi * 8);

  f32x4 o_acc[4] = {};
  float mrow[4] = {-1e30f, -1e30f, -1e30f, -1e30f};
  float lrow[4] = {0.f, 0.f, 0.f, 0.f};

  const int r0 = tid >> 3;          // staging row in 32-row stripe
  const int o16 = (tid & 7) * 16;   // staging byte offset in 128B row
  const int gcb = o16 ^ ((r0 & 7) << 4);   // inverse-swizzled global col (m173); row&7 == r0&7
  char* PsB = (char*)(Ps[w]);

  // stage k-tile kt into buffer b: LDS linear dest + inverse-swizzled global source
  auto STAGE = [&](int b, int kt) {
#pragma unroll
    for (int c = 0; c < 2; ++c) {
      const int row = c * 32 + r0;
      gload_lds16((const char*)Kh + ((size_t)(bh * S + kt * 64 + row) * 64) * 2 + gcb,
                  (char*)(Ks[b]) + (c * 256 + tid) * 16);
      gload_lds16((const char*)Vt + ((size_t)(bh * 64 + row) * S + kt * 64) * 2 + gcb,
                  (char*)(Vs[b]) + (c * 256 + tid) * 16);
    }
  };

  // epilogue: O / l, write attn out as [b][s][h*64+dk] bf16
  const int bb = bh >> 4, hh = bh & 15;
  auto EPILOGUE = [&](int qt) {
#pragma unroll
    for (int r = 0; r < 4; ++r) {
      const float inv = 1.0f / lrow[r];
      const int sg = qt * 64 + w * 16 + lhi * 4 + r;
#pragma unroll
      for (int c = 0; c < 4; ++c)
        Ao[(((size_t)(bb * 2048 + sg) * 16 + hh) << 6) + c * 16 + l15] = f2bfn(o_acc[c][r] * inv);
    }
  };

  const int stepsA = qtA + 1;                 // phase A: kt = 0..qtA
  const int total = stepsA + qtB + 1;         // phase B: kt = 0..qtB  (33 steps every block)

  STAGE(0, 0);
  __syncthreads();                   // full drain: buf0 ready
  int buf = 0;

  for (int step = 0; step < total; ++step) {
    const bool phB = step >= stepsA;
    const int qt = phB ? qtB : qtA;
    const int kt = phB ? step - stepsA : step;

    // prefetch next step's k-tile (crosses the phase boundary seamlessly)
    if (step + 1 < total)
      STAGE(buf ^ 1, (step + 1 >= stepsA) ? step + 1 - stepsA : step + 1);

    const char* KsB = (const char*)(Ks[buf]);
    const char* VsB = (const char*)(Vs[buf]);
    const bf16x8 q0 = phB ? qfB0 : qfA0;
    const bf16x8 q1 = phB ? qfB1 : qfA1;

    // S = Q K^T : B-operand col = s_k (K row), k = d
    f32x4 sA[4];
    __builtin_amdgcn_s_setprio(1);
#pragma unroll
    for (int c = 0; c < 4; ++c) {
      f32x4 z = {};
      const int krow = c * 16 + l15;
      const int swz = (krow & 7) << 4;
      z = __builtin_amdgcn_mfma_f32_16x16x32_bf16(
          q0, *(const bf16x8*)(KsB + ((krow * 128 + lhi * 16) ^ swz)), z, 0, 0, 0);
      z = __builtin_amdgcn_mfma_f32_16x16x32_bf16(
          q1, *(const bf16x8*)(KsB + ((krow * 128 + 64 + lhi * 16) ^ swz)), z, 0, 0, 0);
      sA[c] = z;
    }
    __builtin_amdgcn_s_setprio(0);

    // scale (log2-domain) + causal mask (diagonal band is exactly the kt==qt tile)
    const bool diag = (kt == qt);
#pragma unroll
    for (int c = 0; c < 4; ++c)
#pragma unroll
      for (int r = 0; r < 4; ++r) {
        float sv = sA[c][r] * SCL;
        if (diag && (c * 16 + l15 > w * 16 + lhi * 4 + r)) sv = -1e30f;
        sA[c][r] = sv;
      }

    // online softmax (base-2); S row r lives across the 16 lanes of this lane-group
#pragma unroll
    for (int r = 0; r < 4; ++r) {
      float tm = fmaxf(fmaxf(sA[0][r], sA[1][r]), fmaxf(sA[2][r], sA[3][r]));
      tm = fmaxf(tm, __shfl_xor(tm, 1));
      tm = fmaxf(tm, __shfl_xor(tm, 2));
      tm = fmaxf(tm, __shfl_xor(tm, 4));
      tm = fmaxf(tm, __shfl_xor(tm, 8));
      const float mnew = fmaxf(mrow[r], tm);
      const float sc = __builtin_amdgcn_exp2f(mrow[r] - mnew);
      float rs = 0.f;
#pragma unroll
      for (int c = 0; c < 4; ++c) {
        const float p = __builtin_amdgcn_exp2f(sA[c][r] - mnew);
        sA[c][r] = p;
        rs += p;
      }
      rs += __shfl_xor(rs, 1);
      rs += __shfl_xor(rs, 2);
      rs += __shfl_xor(rs, 4);
      rs += __shfl_xor(rs, 8);
      lrow[r] = lrow[r] * sc + rs;
      mrow[r] = mnew;
#pragma unroll
      for (int c = 0; c < 4; ++c) o_acc[c][r] *= sc;
    }

    // P -> LDS (bf16, swizzled), then read back as PV A-operand (same-wave, lgkm-ordered)
#pragma unroll
    for (int c = 0; c < 4; ++c)
#pragma unroll
      for (int r = 0; r < 4; ++r) {
        const int prow = lhi * 4 + r;
        *(u16*)(PsB + ((prow * 128 + (c * 16 + l15) * 2) ^ ((prow & 7) << 4))) = f2bfn(sA[c][r]);
      }

    bf16x8 pa0 = *(const bf16x8*)(PsB + ((l15 * 128 + lhi * 16) ^ ((l15 & 7) << 4)));
    bf16x8 pa1 = *(const bf16x8*)(PsB + ((l15 * 128 + 64 + lhi * 16) ^ ((l15 & 7) << 4)));
    __builtin_amdgcn_s_setprio(1);
#pragma unroll
    for (int c = 0; c < 4; ++c) {
      const int drow = c * 16 + l15;
      const int swz = (drow & 7) << 4;
      o_acc[c] = __builtin_amdgcn_mfma_f32_16x16x32_bf16(
          pa0, *(const bf16x8*)(VsB + ((drow * 128 + lhi * 16) ^ swz)), o_acc[c], 0, 0, 0);
      o_acc[c] = __builtin_amdgcn_mfma_f32_16x16x32_bf16(
          pa1, *(const bf16x8*)(VsB + ((drow * 128 + 64 + lhi * 16) ^ swz)), o_acc[c], 0, 0, 0);
    }
    __builtin_amdgcn_s_setprio(0);

    __syncthreads();   // drains vmcnt(0): next buf staged + all waves done with this buf
    buf ^= 1;

    // phase boundary: flush phase-A output, reset online-softmax state
    if (step == stepsA - 1) {
      EPILOGUE(qtA);
#pragma unroll
      for (int r = 0; r < 4; ++r) { mrow[r] = -1e30f; lrow[r] = 0.f; }
#pragma unroll
      for (int c = 0; c < 4; ++c) o_acc[c] = f32x4{};
    }
  }

  EPILOGUE(qtB);
}

extern "C" void kernel_launch(void* const* d_in, const int* in_sizes, int n_in,
                              void* d_out, int out_size, void* d_ws, size_t ws_size,
                              hipStream_t stream) {
  const float* q  = (const float*)d_in[0];
  const float* k  = (const float*)d_in[1];
  const float* v  = (const float*)d_in[2];
  // d_in[3] = causal mask (triu k=1) -- structurally known, unused
  const float* wq = (const float*)d_in[4];
  const float* wk = (const float*)d_in[5];
  const float* wv = (const float*)d_in[6];
  const float* wo = (const float*)d_in[7];

  char* ws = (char*)d_ws;
  const size_t SZX = (size_t)8192 * 1024 * 2;   // 16 MB bf16 activation
  const size_t SZW = (size_t)1024 * 1024 * 2;   // 2 MB bf16 weight
  u16* Xq = (u16*)(ws);                         // dead after Q-proj GEMM
  u16* Xk = (u16*)(ws + SZX);
  u16* Xv = (u16*)(ws + 2 * SZX);
  u16* Wq = (u16*)(ws + 3 * SZX);
  u16* Wk = (u16*)(ws + 3 * SZX + SZW);
  u16* Wv = (u16*)(ws + 3 * SZX + 2 * SZW);
  u16* Wo = (u16*)(ws + 3 * SZX + 3 * SZW);
  u16* Qh = (u16*)(ws + 3 * SZX + 4 * SZW);
  u16* Kh = (u16*)(ws + 4 * SZX + 4 * SZW);
  u16* Vt = (u16*)(ws + 5 * SZX + 4 * SZW);
  u16* Ao = Xq;                                  // reuse: Ao written only after Xq is dead
  // peak ws use: 6*16MB + 8MB = ~104 MB

  cvt_bf16<<<dim3(1024, 3), 256, 0, stream>>>(q, k, v, q, Xq, Xk, Xv, Xq, 8388608 / 4);
  cvt_bf16<<<dim3(256, 4), 256, 0, stream>>>(wq, wk, wv, wo, Wq, Wk, Wv, Wo, 1048576 / 4);
  gemm_bt<1><<<dim3(8, 64), 256, 0, stream>>>(Xq, Wq, Qh);
  gemm_bt<1><<<dim3(8, 64), 256, 0, stream>>>(Xk, Wk, Kh);
  gemm_bt<2><<<dim3(8, 64), 256, 0, stream>>>(Xv, Wv, Vt);
  attn_fwd<<<dim3(16, 64), 256, 0, stream>>>(Qh, Kh, Vt, Ao);
  gemm_bt<0><<<dim3(8, 64), 256, 0, stream>>>(Ao, Wo, (float*)d_out);
}

// Round 12
// 360.719 us; speedup vs baseline: 1.3864x; 1.1512x over previous
//
#include <hip/hip_runtime.h>

typedef unsigned short u16;
typedef __bf16 bf16x8 __attribute__((ext_vector_type(8)));
typedef float f32x4 __attribute__((ext_vector_type(4)));

__device__ __forceinline__ u16 f2bf(float f) {
  union { float f; unsigned u; } v; v.f = f;
  unsigned r = v.u + 0x7fffu + ((v.u >> 16) & 1u);
  return (u16)(r >> 16);
}

// native cast form: numerically identical (RNE), lets compiler pack v_cvt_pk_bf16_f32
__device__ __forceinline__ u16 f2bfn(float f) {
  union { __bf16 h; u16 u; } v; v.h = (__bf16)f; return v.u;
}

__device__ __forceinline__ void gload_lds16(const void* g, void* l) {
  using gvp = const __attribute__((address_space(1))) void*;
  using lvp = __attribute__((address_space(3))) void*;
  __builtin_amdgcn_global_load_lds((gvp)g, (lvp)l, 16, 0, 0);
}

// ---------------- fp32 -> bf16 conversion (up to 4 equal-size tensors) ----------------
__global__ void cvt_bf16(const float* __restrict__ s0, const float* __restrict__ s1,
                         const float* __restrict__ s2, const float* __restrict__ s3,
                         u16* __restrict__ d0, u16* __restrict__ d1,
                         u16* __restrict__ d2, u16* __restrict__ d3, int n4) {
  const float* srcs[4] = {s0, s1, s2, s3};
  u16* dsts[4] = {d0, d1, d2, d3};
  const float4* src = (const float4*)srcs[blockIdx.y];
  u16* dst = dsts[blockIdx.y];
  for (int i = blockIdx.x * blockDim.x + threadIdx.x; i < n4; i += gridDim.x * blockDim.x) {
    float4 v = src[i];
    ushort4 o;
    o.x = f2bf(v.x); o.y = f2bf(v.y); o.z = f2bf(v.z); o.w = f2bf(v.w);
    *(ushort4*)(dst + (size_t)i * 4) = o;
  }
}

// ---------------- GEMM: C[m][n] = sum_k A[m][k] * Bw[n][k]  (both bf16 row-major, K inner) ----
// MODE 0: C fp32 plain [M][N]
// MODE 1: C bf16 head-split [b*16+h][s][dk]   (m=b*2048+s, n=h*64+dk)
// MODE 2: C bf16 head-split transposed [b*16+h][dk][s]
template<int MODE>
__global__ __launch_bounds__(256)
void gemm_bt(const u16* __restrict__ A, const u16* __restrict__ Bw, void* __restrict__ Cout) {
  constexpr int N = 1024, K = 1024, BK = 64;
  __shared__ u16 As[128 * BK];   // linear [128][64] bf16, 16 KB
  __shared__ u16 Bs[128 * BK];
  const int tid = threadIdx.x;
  const int lane = tid & 63, wave = tid >> 6;
  const int wm = wave >> 1, wn = wave & 1;        // 2x2 wave grid, each 64x64 out
  const int l15 = lane & 15, lhi = lane >> 4;
  const int m0 = blockIdx.y * 128, n0 = blockIdx.x * 128;
  const int r0 = tid >> 3;          // staging row within 32-row stripe
  const int o8 = (tid & 7) * 8;     // staging col (elements)

  f32x4 acc[4][4] = {};

  for (int kt = 0; kt < K / BK; ++kt) {
    const int kb = kt * BK;
#pragma unroll
    for (int c = 0; c < 4; ++c) {
      const int row = c * 32 + r0;
      gload_lds16(A + (m0 + row) * K + kb + o8, (char*)As + (c * 256 + tid) * 16);
      gload_lds16(Bw + (n0 + row) * K + kb + o8, (char*)Bs + (c * 256 + tid) * 16);
    }
    __syncthreads();
#pragma unroll
    for (int kk = 0; kk < 2; ++kk) {
      bf16x8 a[4], b[4];
#pragma unroll
      for (int i = 0; i < 4; ++i)
        a[i] = *(const bf16x8*)(As + (wm * 64 + i * 16 + l15) * BK + kk * 32 + lhi * 8);
#pragma unroll
      for (int j = 0; j < 4; ++j)
        b[j] = *(const bf16x8*)(Bs + (wn * 64 + j * 16 + l15) * BK + kk * 32 + lhi * 8);
#pragma unroll
      for (int i = 0; i < 4; ++i)
#pragma unroll
        for (int j = 0; j < 4; ++j)
          acc[i][j] = __builtin_amdgcn_mfma_f32_16x16x32_bf16(a[i], b[j], acc[i][j], 0, 0, 0);
    }
    __syncthreads();
  }

#pragma unroll
  for (int i = 0; i < 4; ++i) {
#pragma unroll
    for (int j = 0; j < 4; ++j) {
#pragma unroll
      for (int r = 0; r < 4; ++r) {
        const int mg = m0 + wm * 64 + i * 16 + lhi * 4 + r;   // C/D: row=(lane>>4)*4+reg
        const int ng = n0 + wn * 64 + j * 16 + l15;           //      col=lane&15
        const float v = acc[i][j][r];
        if (MODE == 0) {
          ((float*)Cout)[(size_t)mg * N + ng] = v;
        } else {
          const int b = mg >> 11, s = mg & 2047, h = ng >> 6, dk = ng & 63;
          if (MODE == 1)
            ((u16*)Cout)[(((size_t)(b * 16 + h) * 2048 + s) << 6) + dk] = f2bf(v);
          else
            ((u16*)Cout)[((size_t)(b * 16 + h) * 64 + dk) * 2048 + s] = f2bf(v);
        }
      }
    }
  }
}

// ---------------- causal flash attention (paired q-tiles, swapped QK^T in-reg softmax) ----
// Q,Kh: [bh][s][64] bf16.  Vt: [bh][64][s] bf16 (transposed).  Ao: [b][s][h][64] bf16.
// Block: 256 thr = 4 waves; each wave owns 16 q-rows; q-tile = 64 rows.
// Swapped S^T = mfma(K,Q): lane holds S[key=c*16+lhi*4+r][q=l15] -> softmax row is
// lane-local (15-op tree + 2 shfl_xor) instead of 32 dependent shuffles.
__global__ __launch_bounds__(256)
void attn_fwd(const u16* __restrict__ Q, const u16* __restrict__ Kh,
              const u16* __restrict__ Vt, u16* __restrict__ Ao) {
  constexpr int S = 2048;
  constexpr float SCL = 0.125f * 1.44269504088896f;   // (1/sqrt(64)) * log2(e)
  __shared__ u16 Ks[2][64 * 64];   // [buf][s_k][d] swizzled: byte ^ ((row&7)<<4)
  __shared__ u16 Vs[2][64 * 64];   // [buf][d][s_k] swizzled
  __shared__ u16 Ps[4][16 * 64];   // per-wave P tile [q][s_k] swizzled
  const int tid = threadIdx.x;
  const int lane = tid & 63, w = tid >> 6;
  const int l15 = lane & 15, lhi = lane >> 4;
  const int bh = blockIdx.y;
  const int qtA = 31 - (int)blockIdx.x;      // big phase first
  const int qtB = (int)blockIdx.x;

  // Q fragments for both phases: row/col=lane&15=q, k=(lane>>4)*8+j
  const u16* QbA = Q + ((size_t)bh * S + qtA * 64 + w * 16 + l15) * 64;
  const u16* QbB = Q + ((size_t)bh * S + qtB * 64 + w * 16 + l15) * 64;
  const bf16x8 qfA0 = *(const bf16x8*)(QbA + lhi * 8);
  const bf16x8 qfA1 = *(const bf16x8*)(QbA + 32 + lhi * 8);
  const bf16x8 qfB0 = *(const bf16x8*)(QbB + lhi * 8);
  const bf16x8 qfB1 = *(const bf16x8*)(QbB + 32 + lhi * 8);

  f32x4 o_acc[4] = {};                 // O[q=w*16+lhi*4+r][d=c*16+l15]
  float mrow = -1e30f, lrow = 0.f;     // online state for q = w*16 + l15 (lane-local)

  const int r0 = tid >> 3;          // staging row in 32-row stripe
  const int o16 = (tid & 7) * 16;   // staging byte offset in 128B row
  const int gcb = o16 ^ ((r0 & 7) << 4);   // inverse-swizzled global col (m173)
  char* PsB = (char*)(Ps[w]);

  // stage k-tile kt into buffer b: LDS linear dest + inverse-swizzled global source
  auto STAGE = [&](int b, int kt) {
#pragma unroll
    for (int c = 0; c < 2; ++c) {
      const int row = c * 32 + r0;
      gload_lds16((const char*)Kh + ((size_t)(bh * S + kt * 64 + row) * 64) * 2 + gcb,
                  (char*)(Ks[b]) + (c * 256 + tid) * 16);
      gload_lds16((const char*)Vt + ((size_t)(bh * 64 + row) * S + kt * 64) * 2 + gcb,
                  (char*)(Vs[b]) + (c * 256 + tid) * 16);
    }
  };

  // epilogue: O / l  (lrow lives in lane l15=q; o_acc rows are q=lhi*4+r -> shfl)
  const int bb = bh >> 4, hh = bh & 15;
  auto EPILOGUE = [&](int qt) {
#pragma unroll
    for (int r = 0; r < 4; ++r) {
      const float inv = 1.0f / __shfl(lrow, lhi * 4 + r);
      const int sg = qt * 64 + w * 16 + lhi * 4 + r;
#pragma unroll
      for (int c = 0; c < 4; ++c)
        Ao[(((size_t)(bb * 2048 + sg) * 16 + hh) << 6) + c * 16 + l15] = f2bfn(o_acc[c][r] * inv);
    }
  };

  const int stepsA = qtA + 1;                 // phase A: kt = 0..qtA
  const int total = stepsA + qtB + 1;         // phase B: kt = 0..qtB  (33 steps every block)

  STAGE(0, 0);
  __syncthreads();                   // full drain: buf0 ready
  int buf = 0;

  for (int step = 0; step < total; ++step) {
    const bool phB = step >= stepsA;
    const int qt = phB ? qtB : qtA;
    const int kt = phB ? step - stepsA : step;

    // prefetch next step's k-tile (crosses the phase boundary seamlessly)
    if (step + 1 < total)
      STAGE(buf ^ 1, (step + 1 >= stepsA) ? step + 1 - stepsA : step + 1);

    const char* KsB = (const char*)(Ks[buf]);
    const char* VsB = (const char*)(Vs[buf]);
    const bf16x8 q0 = phB ? qfB0 : qfA0;
    const bf16x8 q1 = phB ? qfB1 : qfA1;

    // S^T = K Q^T (swapped): A=K-fragment, B=Q-fragment. Same LDS reads as before.
    f32x4 sA[4];
    __builtin_amdgcn_s_setprio(1);
#pragma unroll
    for (int c = 0; c < 4; ++c) {
      f32x4 z = {};
      const int krow = c * 16 + l15;
      const int swz = (krow & 7) << 4;
      z = __builtin_amdgcn_mfma_f32_16x16x32_bf16(
          *(const bf16x8*)(KsB + ((krow * 128 + lhi * 16) ^ swz)), q0, z, 0, 0, 0);
      z = __builtin_amdgcn_mfma_f32_16x16x32_bf16(
          *(const bf16x8*)(KsB + ((krow * 128 + 64 + lhi * 16) ^ swz)), q1, z, 0, 0, 0);
      sA[c] = z;
    }
    __builtin_amdgcn_s_setprio(0);

    // scale (log2-domain) + causal mask; key = kt*64 + c*16+lhi*4+r, q = qt*64 + w*16+l15
    const bool diag = (kt == qt);
#pragma unroll
    for (int c = 0; c < 4; ++c)
#pragma unroll
      for (int r = 0; r < 4; ++r) {
        float sv = sA[c][r] * SCL;
        if (diag && (c * 16 + lhi * 4 + r > w * 16 + l15)) sv = -1e30f;
        sA[c][r] = sv;
      }

    // online softmax: lane owns the full 16-value slice of row q=l15 (+3 partner lanes)
    f32x4 m4 = sA[0];
#pragma unroll
    for (int c = 1; c < 4; ++c)
#pragma unroll
      for (int r = 0; r < 4; ++r) m4[r] = fmaxf(m4[r], sA[c][r]);
    float tm = fmaxf(fmaxf(m4[0], m4[1]), fmaxf(m4[2], m4[3]));
    tm = fmaxf(tm, __shfl_xor(tm, 16));
    tm = fmaxf(tm, __shfl_xor(tm, 32));
    const float mnew = fmaxf(mrow, tm);
    const float sc = __builtin_amdgcn_exp2f(mrow - mnew);
    f32x4 s4 = {};
#pragma unroll
    for (int c = 0; c < 4; ++c)
#pragma unroll
      for (int r = 0; r < 4; ++r) {
        const float p = __builtin_amdgcn_exp2f(sA[c][r] - mnew);
        sA[c][r] = p;
        s4[r] += p;
      }
    float rs = (s4[0] + s4[1]) + (s4[2] + s4[3]);
    rs += __shfl_xor(rs, 16);
    rs += __shfl_xor(rs, 32);
    lrow = lrow * sc + rs;
    mrow = mnew;

    // rescale o_acc: its rows are q=lhi*4+r; fetch that row's sc from lane (lhi*4+r)
    {
      float scr[4];
#pragma unroll
      for (int r = 0; r < 4; ++r) scr[r] = __shfl(sc, lhi * 4 + r);
#pragma unroll
      for (int c = 0; c < 4; ++c)
#pragma unroll
        for (int r = 0; r < 4; ++r) o_acc[c][r] *= scr[r];
    }

    // P -> Ps[q][s_k] (bf16, swizzled): lane's 4 r-values are contiguous -> 4x ds_write_b64
#pragma unroll
    for (int c = 0; c < 4; ++c) {
      union { u16 h[4]; unsigned long long ll; } pk;
#pragma unroll
      for (int r = 0; r < 4; ++r) pk.h[r] = f2bfn(sA[c][r]);
      const int base = l15 * 128 + c * 32 + lhi * 8;   // q=l15, s_k=c*16+lhi*4+r
      *(unsigned long long*)(PsB + (base ^ ((l15 & 7) << 4))) = pk.ll;
    }

    bf16x8 pa0 = *(const bf16x8*)(PsB + ((l15 * 128 + lhi * 16) ^ ((l15 & 7) << 4)));
    bf16x8 pa1 = *(const bf16x8*)(PsB + ((l15 * 128 + 64 + lhi * 16) ^ ((l15 & 7) << 4)));
    __builtin_amdgcn_s_setprio(1);
#pragma unroll
    for (int c = 0; c < 4; ++c) {
      const int drow = c * 16 + l15;
      const int swz = (drow & 7) << 4;
      o_acc[c] = __builtin_amdgcn_mfma_f32_16x16x32_bf16(
          pa0, *(const bf16x8*)(VsB + ((drow * 128 + lhi * 16) ^ swz)), o_acc[c], 0, 0, 0);
      o_acc[c] = __builtin_amdgcn_mfma_f32_16x16x32_bf16(
          pa1, *(const bf16x8*)(VsB + ((drow * 128 + 64 + lhi * 16) ^ swz)), o_acc[c], 0, 0, 0);
    }
    __builtin_amdgcn_s_setprio(0);

    __syncthreads();   // drains vmcnt(0): next buf staged + all waves done with this buf
    buf ^= 1;

    // phase boundary: flush phase-A output, reset online-softmax state
    if (step == stepsA - 1) {
      EPILOGUE(qtA);
      mrow = -1e30f; lrow = 0.f;
#pragma unroll
      for (int c = 0; c < 4; ++c) o_acc[c] = f32x4{};
    }
  }

  EPILOGUE(qtB);
}

extern "C" void kernel_launch(void* const* d_in, const int* in_sizes, int n_in,
                              void* d_out, int out_size, void* d_ws, size_t ws_size,
                              hipStream_t stream) {
  const float* q  = (const float*)d_in[0];
  const float* k  = (const float*)d_in[1];
  const float* v  = (const float*)d_in[2];
  // d_in[3] = causal mask (triu k=1) -- structurally known, unused
  const float* wq = (const float*)d_in[4];
  const float* wk = (const float*)d_in[5];
  const float* wv = (const float*)d_in[6];
  const float* wo = (const float*)d_in[7];

  char* ws = (char*)d_ws;
  const size_t SZX = (size_t)8192 * 1024 * 2;   // 16 MB bf16 activation
  const size_t SZW = (size_t)1024 * 1024 * 2;   // 2 MB bf16 weight
  u16* Xq = (u16*)(ws);                         // dead after Q-proj GEMM
  u16* Xk = (u16*)(ws + SZX);
  u16* Xv = (u16*)(ws + 2 * SZX);
  u16* Wq = (u16*)(ws + 3 * SZX);
  u16* Wk = (u16*)(ws + 3 * SZX + SZW);
  u16* Wv = (u16*)(ws + 3 * SZX + 2 * SZW);
  u16* Wo = (u16*)(ws + 3 * SZX + 3 * SZW);
  u16* Qh = (u16*)(ws + 3 * SZX + 4 * SZW);
  u16* Kh = (u16*)(ws + 4 * SZX + 4 * SZW);
  u16* Vt = (u16*)(ws + 5 * SZX + 4 * SZW);
  u16* Ao = Xq;                                  // reuse: Ao written only after Xq is dead
  // peak ws use: 6*16MB + 8MB = ~104 MB

  cvt_bf16<<<dim3(1024, 3), 256, 0, stream>>>(q, k, v, q, Xq, Xk, Xv, Xq, 8388608 / 4);
  cvt_bf16<<<dim3(256, 4), 256, 0, stream>>>(wq, wk, wv, wo, Wq, Wk, Wv, Wo, 1048576 / 4);
  gemm_bt<1><<<dim3(8, 64), 256, 0, stream>>>(Xq, Wq, Qh);
  gemm_bt<1><<<dim3(8, 64), 256, 0, stream>>>(Xk, Wk, Kh);
  gemm_bt<2><<<dim3(8, 64), 256, 0, stream>>>(Xv, Wv, Vt);
  attn_fwd<<<dim3(16, 64), 256, 0, stream>>>(Qh, Kh, Vt, Ao);
  gemm_bt<0><<<dim3(8, 64), 256, 0, stream>>>(Ao, Wo, (float*)d_out);
}

// Round 13
// 352.415 us; speedup vs baseline: 1.4191x; 1.0236x over previous
//
#include <hip/hip_runtime.h>

typedef unsigned short u16;
typedef __bf16 bf16x8 __attribute__((ext_vector_type(8)));
typedef float f32x4 __attribute__((ext_vector_type(4)));

__device__ __forceinline__ u16 f2bf(float f) {
  union { float f; unsigned u; } v; v.f = f;
  unsigned r = v.u + 0x7fffu + ((v.u >> 16) & 1u);
  return (u16)(r >> 16);
}

// native cast form: numerically identical (RNE), lets compiler pack v_cvt_pk_bf16_f32
__device__ __forceinline__ u16 f2bfn(float f) {
  union { __bf16 h; u16 u; } v; v.h = (__bf16)f; return v.u;
}

__device__ __forceinline__ void gload_lds16(const void* g, void* l) {
  using gvp = const __attribute__((address_space(1))) void*;
  using lvp = __attribute__((address_space(3))) void*;
  __builtin_amdgcn_global_load_lds((gvp)g, (lvp)l, 16, 0, 0);
}

// ---------------- fp32 -> bf16 conversion (up to 4 equal-size tensors) ----------------
__global__ void cvt_bf16(const float* __restrict__ s0, const float* __restrict__ s1,
                         const float* __restrict__ s2, const float* __restrict__ s3,
                         u16* __restrict__ d0, u16* __restrict__ d1,
                         u16* __restrict__ d2, u16* __restrict__ d3, int n4) {
  const float* srcs[4] = {s0, s1, s2, s3};
  u16* dsts[4] = {d0, d1, d2, d3};
  const float4* src = (const float4*)srcs[blockIdx.y];
  u16* dst = dsts[blockIdx.y];
  for (int i = blockIdx.x * blockDim.x + threadIdx.x; i < n4; i += gridDim.x * blockDim.x) {
    float4 v = src[i];
    ushort4 o;
    o.x = f2bf(v.x); o.y = f2bf(v.y); o.z = f2bf(v.z); o.w = f2bf(v.w);
    *(ushort4*)(dst + (size_t)i * 4) = o;
  }
}

// ---------------- GEMM: C[m][n] = sum_k A[m][k] * Bw[n][k]  (both bf16 row-major, K inner) ----
// Grid is (m-blocks, n-blocks) = (64, 8): linear bid = mblk + 64*nblk -> XCD = mblk%8.
// Per-XCD working set: A-stripe 8x256KB = 2MB + B 2MB = L2-resident (A read ~1x from HBM).
// MODE 0: C fp32 plain [M][N]
// MODE 1: C bf16 head-split [b*16+h][s][dk]   (m=b*2048+s, n=h*64+dk)
// MODE 2: C bf16 head-split transposed [b*16+h][dk][s]
template<int MODE>
__global__ __launch_bounds__(256)
void gemm_bt(const u16* __restrict__ A, const u16* __restrict__ Bw, void* __restrict__ Cout) {
  constexpr int N = 1024, K = 1024, BK = 64;
  __shared__ u16 As[128 * BK];   // linear [128][64] bf16, 16 KB
  __shared__ u16 Bs[128 * BK];
  const int tid = threadIdx.x;
  const int lane = tid & 63, wave = tid >> 6;
  const int wm = wave >> 1, wn = wave & 1;        // 2x2 wave grid, each 64x64 out
  const int l15 = lane & 15, lhi = lane >> 4;
  const int m0 = blockIdx.x * 128, n0 = blockIdx.y * 128;   // m-major grid (XCD locality)
  const int r0 = tid >> 3;          // staging row within 32-row stripe
  const int o8 = (tid & 7) * 8;     // staging col (elements)

  f32x4 acc[4][4] = {};

  for (int kt = 0; kt < K / BK; ++kt) {
    const int kb = kt * BK;
#pragma unroll
    for (int c = 0; c < 4; ++c) {
      const int row = c * 32 + r0;
      gload_lds16(A + (m0 + row) * K + kb + o8, (char*)As + (c * 256 + tid) * 16);
      gload_lds16(Bw + (n0 + row) * K + kb + o8, (char*)Bs + (c * 256 + tid) * 16);
    }
    __syncthreads();
#pragma unroll
    for (int kk = 0; kk < 2; ++kk) {
      bf16x8 a[4], b[4];
#pragma unroll
      for (int i = 0; i < 4; ++i)
        a[i] = *(const bf16x8*)(As + (wm * 64 + i * 16 + l15) * BK + kk * 32 + lhi * 8);
#pragma unroll
      for (int j = 0; j < 4; ++j)
        b[j] = *(const bf16x8*)(Bs + (wn * 64 + j * 16 + l15) * BK + kk * 32 + lhi * 8);
#pragma unroll
      for (int i = 0; i < 4; ++i)
#pragma unroll
        for (int j = 0; j < 4; ++j)
          acc[i][j] = __builtin_amdgcn_mfma_f32_16x16x32_bf16(a[i], b[j], acc[i][j], 0, 0, 0);
    }
    __syncthreads();
  }

#pragma unroll
  for (int i = 0; i < 4; ++i) {
#pragma unroll
    for (int j = 0; j < 4; ++j) {
#pragma unroll
      for (int r = 0; r < 4; ++r) {
        const int mg = m0 + wm * 64 + i * 16 + lhi * 4 + r;   // C/D: row=(lane>>4)*4+reg
        const int ng = n0 + wn * 64 + j * 16 + l15;           //      col=lane&15
        const float v = acc[i][j][r];
        if (MODE == 0) {
          ((float*)Cout)[(size_t)mg * N + ng] = v;
        } else {
          const int b = mg >> 11, s = mg & 2047, h = ng >> 6, dk = ng & 63;
          if (MODE == 1)
            ((u16*)Cout)[(((size_t)(b * 16 + h) * 2048 + s) << 6) + dk] = f2bf(v);
          else
            ((u16*)Cout)[((size_t)(b * 16 + h) * 64 + dk) * 2048 + s] = f2bf(v);
        }
      }
    }
  }
}

// ---------------- causal flash attention (paired q-tiles, swapped QK^T, defer-max) ----
// Q,Kh: [bh][s][64] bf16.  Vt: [bh][64][s] bf16 (transposed).  Ao: [b][s][h][64] bf16.
// Grid (bh, qpair) = (64, 16): XCD = bh%8 -> per-XCD K/V = 8bh x 512KB = 4MB, L2-resident.
// Swapped S^T = mfma(K,Q): lane holds S[key=c*16+lhi*4+r][q=l15] -> softmax lane-local.
__global__ __launch_bounds__(256)
void attn_fwd(const u16* __restrict__ Q, const u16* __restrict__ Kh,
              const u16* __restrict__ Vt, u16* __restrict__ Ao) {
  constexpr int S = 2048;
  constexpr float SCL = 0.125f * 1.44269504088896f;   // (1/sqrt(64)) * log2(e)
  __shared__ u16 Ks[2][64 * 64];   // [buf][s_k][d] swizzled: byte ^ ((row&7)<<4)
  __shared__ u16 Vs[2][64 * 64];   // [buf][d][s_k] swizzled
  __shared__ u16 Ps[4][16 * 64];   // per-wave P tile [q][s_k] swizzled
  const int tid = threadIdx.x;
  const int lane = tid & 63, w = tid >> 6;
  const int l15 = lane & 15, lhi = lane >> 4;
  const int bh = blockIdx.x;                 // XCD = bh%8
  const int qtA = 31 - (int)blockIdx.y;      // big phase first
  const int qtB = (int)blockIdx.y;

  // Q fragments for both phases: row/col=lane&15=q, k=(lane>>4)*8+j
  const u16* QbA = Q + ((size_t)bh * S + qtA * 64 + w * 16 + l15) * 64;
  const u16* QbB = Q + ((size_t)bh * S + qtB * 64 + w * 16 + l15) * 64;
  const bf16x8 qfA0 = *(const bf16x8*)(QbA + lhi * 8);
  const bf16x8 qfA1 = *(const bf16x8*)(QbA + 32 + lhi * 8);
  const bf16x8 qfB0 = *(const bf16x8*)(QbB + lhi * 8);
  const bf16x8 qfB1 = *(const bf16x8*)(QbB + 32 + lhi * 8);

  f32x4 o_acc[4] = {};                 // O[q=w*16+lhi*4+r][d=c*16+l15]
  float mrow = -1e30f, lrow = 0.f;     // online state for q = w*16 + l15 (lane-local)

  const int r0 = tid >> 3;          // staging row in 32-row stripe
  const int o16 = (tid & 7) * 16;   // staging byte offset in 128B row
  const int gcb = o16 ^ ((r0 & 7) << 4);   // inverse-swizzled global col (m173)
  char* PsB = (char*)(Ps[w]);

  // stage k-tile kt into buffer b: LDS linear dest + inverse-swizzled global source
  auto STAGE = [&](int b, int kt) {
#pragma unroll
    for (int c = 0; c < 2; ++c) {
      const int row = c * 32 + r0;
      gload_lds16((const char*)Kh + ((size_t)(bh * S + kt * 64 + row) * 64) * 2 + gcb,
                  (char*)(Ks[b]) + (c * 256 + tid) * 16);
      gload_lds16((const char*)Vt + ((size_t)(bh * 64 + row) * S + kt * 64) * 2 + gcb,
                  (char*)(Vs[b]) + (c * 256 + tid) * 16);
    }
  };

  // epilogue: O / l  (lrow lives in lane l15=q; o_acc rows are q=lhi*4+r -> shfl)
  const int bb = bh >> 4, hh = bh & 15;
  auto EPILOGUE = [&](int qt) {
#pragma unroll
    for (int r = 0; r < 4; ++r) {
      const float inv = 1.0f / __shfl(lrow, lhi * 4 + r);
      const int sg = qt * 64 + w * 16 + lhi * 4 + r;
#pragma unroll
      for (int c = 0; c < 4; ++c)
        Ao[(((size_t)(bb * 2048 + sg) * 16 + hh) << 6) + c * 16 + l15] = f2bfn(o_acc[c][r] * inv);
    }
  };

  const int stepsA = qtA + 1;                 // phase A: kt = 0..qtA
  const int total = stepsA + qtB + 1;         // phase B: kt = 0..qtB  (33 steps every block)

  STAGE(0, 0);
  __syncthreads();                   // full drain: buf0 ready
  int buf = 0;

  for (int step = 0; step < total; ++step) {
    const bool phB = step >= stepsA;
    const int qt = phB ? qtB : qtA;
    const int kt = phB ? step - stepsA : step;

    // prefetch next step's k-tile (crosses the phase boundary seamlessly)
    if (step + 1 < total)
      STAGE(buf ^ 1, (step + 1 >= stepsA) ? step + 1 - stepsA : step + 1);

    const char* KsB = (const char*)(Ks[buf]);
    const char* VsB = (const char*)(Vs[buf]);
    const bf16x8 q0 = phB ? qfB0 : qfA0;
    const bf16x8 q1 = phB ? qfB1 : qfA1;

    // S^T = K Q^T (swapped): A=K-fragment, B=Q-fragment. Same LDS reads as before.
    f32x4 sA[4];
    __builtin_amdgcn_s_setprio(1);
#pragma unroll
    for (int c = 0; c < 4; ++c) {
      f32x4 z = {};
      const int krow = c * 16 + l15;
      const int swz = (krow & 7) << 4;
      z = __builtin_amdgcn_mfma_f32_16x16x32_bf16(
          *(const bf16x8*)(KsB + ((krow * 128 + lhi * 16) ^ swz)), q0, z, 0, 0, 0);
      z = __builtin_amdgcn_mfma_f32_16x16x32_bf16(
          *(const bf16x8*)(KsB + ((krow * 128 + 64 + lhi * 16) ^ swz)), q1, z, 0, 0, 0);
      sA[c] = z;
    }
    __builtin_amdgcn_s_setprio(0);

    // scale (log2-domain) + causal mask; key = kt*64 + c*16+lhi*4+r, q = qt*64 + w*16+l15
    const bool diag = (kt == qt);
#pragma unroll
    for (int c = 0; c < 4; ++c)
#pragma unroll
      for (int r = 0; r < 4; ++r) {
        float sv = sA[c][r] * SCL;
        if (diag && (c * 16 + lhi * 4 + r > w * 16 + l15)) sv = -1e30f;
        sA[c][r] = sv;
      }

    // online softmax: lane owns the full 16-value slice of row q=l15 (+3 partner lanes)
    f32x4 m4 = sA[0];
#pragma unroll
    for (int c = 1; c < 4; ++c)
#pragma unroll
      for (int r = 0; r < 4; ++r) m4[r] = fmaxf(m4[r], sA[c][r]);
    float tm = fmaxf(fmaxf(m4[0], m4[1]), fmaxf(m4[2], m4[3]));
    tm = fmaxf(tm, __shfl_xor(tm, 16));
    tm = fmaxf(tm, __shfl_xor(tm, 32));

    // defer-max (T13): only rescale when some row's max grew past mrow+8 (P <= 2^8 safe)
    if (__any(tm > mrow + 8.0f)) {
      const float mnew = fmaxf(mrow, tm);
      const float sc = __builtin_amdgcn_exp2f(mrow - mnew);
      mrow = mnew;
      lrow *= sc;
      float scr[4];
#pragma unroll
      for (int r = 0; r < 4; ++r) scr[r] = __shfl(sc, lhi * 4 + r);
#pragma unroll
      for (int c = 0; c < 4; ++c)
#pragma unroll
        for (int r = 0; r < 4; ++r) o_acc[c][r] *= scr[r];
    }

    f32x4 s4 = {};
#pragma unroll
    for (int c = 0; c < 4; ++c)
#pragma unroll
      for (int r = 0; r < 4; ++r) {
        const float p = __builtin_amdgcn_exp2f(sA[c][r] - mrow);
        sA[c][r] = p;
        s4[r] += p;
      }
    float rs = (s4[0] + s4[1]) + (s4[2] + s4[3]);
    rs += __shfl_xor(rs, 16);
    rs += __shfl_xor(rs, 32);
    lrow += rs;

    // P -> Ps[q][s_k] (bf16, swizzled): lane's 4 r-values are contiguous -> 4x ds_write_b64
#pragma unroll
    for (int c = 0; c < 4; ++c) {
      union { u16 h[4]; unsigned long long ll; } pk;
#pragma unroll
      for (int r = 0; r < 4; ++r) pk.h[r] = f2bfn(sA[c][r]);
      const int base = l15 * 128 + c * 32 + lhi * 8;   // q=l15, s_k=c*16+lhi*4+r
      *(unsigned long long*)(PsB + (base ^ ((l15 & 7) << 4))) = pk.ll;
    }

    bf16x8 pa0 = *(const bf16x8*)(PsB + ((l15 * 128 + lhi * 16) ^ ((l15 & 7) << 4)));
    bf16x8 pa1 = *(const bf16x8*)(PsB + ((l15 * 128 + 64 + lhi * 16) ^ ((l15 & 7) << 4)));
    __builtin_amdgcn_s_setprio(1);
#pragma unroll
    for (int c = 0; c < 4; ++c) {
      const int drow = c * 16 + l15;
      const int swz = (drow & 7) << 4;
      o_acc[c] = __builtin_amdgcn_mfma_f32_16x16x32_bf16(
          pa0, *(const bf16x8*)(VsB + ((drow * 128 + lhi * 16) ^ swz)), o_acc[c], 0, 0, 0);
      o_acc[c] = __builtin_amdgcn_mfma_f32_16x16x32_bf16(
          pa1, *(const bf16x8*)(VsB + ((drow * 128 + 64 + lhi * 16) ^ swz)), o_acc[c], 0, 0, 0);
    }
    __builtin_amdgcn_s_setprio(0);

    __syncthreads();   // drains vmcnt(0): next buf staged + all waves done with this buf
    buf ^= 1;

    // phase boundary: flush phase-A output, reset online-softmax state
    if (step == stepsA - 1) {
      EPILOGUE(qtA);
      mrow = -1e30f; lrow = 0.f;
#pragma unroll
      for (int c = 0; c < 4; ++c) o_acc[c] = f32x4{};
    }
  }

  EPILOGUE(qtB);
}

extern "C" void kernel_launch(void* const* d_in, const int* in_sizes, int n_in,
                              void* d_out, int out_size, void* d_ws, size_t ws_size,
                              hipStream_t stream) {
  const float* q  = (const float*)d_in[0];
  const float* k  = (const float*)d_in[1];
  const float* v  = (const float*)d_in[2];
  // d_in[3] = causal mask (triu k=1) -- structurally known, unused
  const float* wq = (const float*)d_in[4];
  const float* wk = (const float*)d_in[5];
  const float* wv = (const float*)d_in[6];
  const float* wo = (const float*)d_in[7];

  char* ws = (char*)d_ws;
  const size_t SZX = (size_t)8192 * 1024 * 2;   // 16 MB bf16 activation
  const size_t SZW = (size_t)1024 * 1024 * 2;   // 2 MB bf16 weight
  u16* Xq = (u16*)(ws);                         // dead after Q-proj GEMM
  u16* Xk = (u16*)(ws + SZX);
  u16* Xv = (u16*)(ws + 2 * SZX);
  u16* Wq = (u16*)(ws + 3 * SZX);
  u16* Wk = (u16*)(ws + 3 * SZX + SZW);
  u16* Wv = (u16*)(ws + 3 * SZX + 2 * SZW);
  u16* Wo = (u16*)(ws + 3 * SZX + 3 * SZW);
  u16* Qh = (u16*)(ws + 3 * SZX + 4 * SZW);
  u16* Kh = (u16*)(ws + 4 * SZX + 4 * SZW);
  u16* Vt = (u16*)(ws + 5 * SZX + 4 * SZW);
  u16* Ao = Xq;                                  // reuse: Ao written only after Xq is dead
  // peak ws use: 6*16MB + 8MB = ~104 MB

  cvt_bf16<<<dim3(1024, 3), 256, 0, stream>>>(q, k, v, q, Xq, Xk, Xv, Xq, 8388608 / 4);
  cvt_bf16<<<dim3(256, 4), 256, 0, stream>>>(wq, wk, wv, wo, Wq, Wk, Wv, Wo, 1048576 / 4);
  gemm_bt<1><<<dim3(64, 8), 256, 0, stream>>>(Xq, Wq, Qh);
  gemm_bt<1><<<dim3(64, 8), 256, 0, stream>>>(Xk, Wk, Kh);
  gemm_bt<2><<<dim3(64, 8), 256, 0, stream>>>(Xv, Wv, Vt);
  attn_fwd<<<dim3(64, 16), 256, 0, stream>>>(Qh, Kh, Vt, Ao);
  gemm_bt<0><<<dim3(64, 8), 256, 0, stream>>>(Ao, Wo, (float*)d_out);
}